// Round 15
// baseline (3063.957 us; speedup 1.0000x reference)
//
#include <hip/hip_runtime.h>
#include <hip/hip_fp16.h>

#define H 1024
#define B 512
#define T 512
#define NC 10

#define NGROUPS 16      // batch-slice groups (32 batches each)
#define WPG 16          // WGs per group (M slices)
#define NSLICE 32       // batches per group
#define MROWS 64        // H rows per WG
#define FLAG_STRIDE 16  // 16 u32 = 64B per flag line

typedef _Float16 f16x8 __attribute__((ext_vector_type(8)));
typedef _Float16 f16x4 __attribute__((ext_vector_type(4)));
typedef float    f32x4 __attribute__((ext_vector_type(4)));
typedef unsigned u32x4 __attribute__((ext_vector_type(4)));
typedef unsigned long long ull;

__device__ __forceinline__ float fast_tanh(float x) {
    float e = __expf(2.0f * x);
    return 1.0f - 2.0f / (e + 1.0f);
}

// ---- W_hh f32 -> f16 row-major ----
__global__ void convert_w(const float* __restrict__ w, _Float16* __restrict__ o) {
    int i = (blockIdx.x * 256 + threadIdx.x) * 4;
    float4 v = *(const float4*)(w + i);
    f16x4 r;
    r[0] = (_Float16)v.x; r[1] = (_Float16)v.y;
    r[2] = (_Float16)v.z; r[3] = (_Float16)v.w;
    *(f16x4*)(o + i) = r;
}

// ---- x [B][T] -> xT [T][B] ----
__global__ void transpose_x(const float* __restrict__ x, float* __restrict__ xT) {
    __shared__ float tile[32][33];
    const int tx = threadIdx.x & 31;
    const int ty = threadIdx.x >> 5;
    const int t0 = blockIdx.x * 32;
    const int b0 = blockIdx.y * 32;
    #pragma unroll
    for (int i = ty; i < 32; i += 8)
        tile[i][tx] = x[(size_t)(b0 + i) * T + t0 + tx];
    __syncthreads();
    #pragma unroll
    for (int i = ty; i < 32; i += 8)
        xT[(size_t)(t0 + i) * B + b0 + tx] = tile[tx][i];
}

// h load: sc0 only -> bypass own stale L1, served by the XCD-shared L2
#define G_LOAD_X4(dst, addr, OFF) \
    asm volatile("global_load_dwordx4 %0, %1, off offset:" OFF " sc0" \
                 : "=&v"(dst) : "v"(addr) : "memory")

#define ISSUE8(arr, base) do { \
    G_LOAD_X4(arr[0], (base), "0");   G_LOAD_X4(arr[1], (base), "64");  \
    G_LOAD_X4(arr[2], (base), "128"); G_LOAD_X4(arr[3], (base), "192"); \
    G_LOAD_X4(arr[4], (base), "256"); G_LOAD_X4(arr[5], (base), "320"); \
    G_LOAD_X4(arr[6], (base), "384"); G_LOAD_X4(arr[7], (base), "448"); \
} while (0)

// h store: sc0 -> coherent write-through to the XCD-shared L2 (stops at L2)
#define G_STORE_X2(addr, data) \
    asm volatile("global_store_dwordx2 %0, %1, off sc0" \
                 :: "v"(addr), "v"(data) : "memory")

// flag poll: agent-scope load (MALL) — proven prompt-visibility path
#define PISSUE(v) \
    asm volatile("global_load_dword %0, %1, off sc0 sc1" \
                 : "=&v"(v) : "v"(fpoll) : "memory")

// ---- persistent RNN: 256 WGs x 256 thr (4 waves) ----
// R13 structure verbatim (h in XCD L2 via sc0; dynamic XCD grouping; W in
// LDS; per-consumer-replicated MALL flags; wave0 polls, syncthreads
// releases). SINGLE change: wave0 sleeps ~1.3us BEFORE polling — flags
// cannot have committed earlier anyway, and removing the futile early poll
// rounds decongests the MALL so publish/pickup latency drops for everyone.
__global__ void __launch_bounds__(256, 1) rnn_persist(
        const _Float16* __restrict__ Wf, const float* __restrict__ xT,
        const float* __restrict__ Whx, const float* __restrict__ bh,
        _Float16* h0, _Float16* h1, unsigned* flags, unsigned* claim) {

    __shared__ _Float16 Wlds[MROWS * H];   // 128 KB -> exactly 1 WG/CU
    __shared__ int s_g, s_ms;

    const int tid  = threadIdx.x;
    const int wave = tid >> 6;
    const int lane = tid & 63;
    const int lm   = lane & 15;
    const int kg   = lane >> 4;
    const int wm   = wave >> 1;            // M half 0..1
    const int wn   = wave & 1;             // N half 0..1

    // ---- dynamic XCD grouping (capacity-forced: exactly 32 WGs per XCD) ----
    if (tid == 0) {
        unsigned xcd;
        asm volatile("s_getreg_b32 %0, hwreg(HW_REG_XCC_ID)" : "=s"(xcd));
        xcd &= 7;
        unsigned slot = atomicAdd(&claim[xcd], 1u);   // 0..31 per XCD
        s_ms = (int)(slot & 15);
        s_g  = (int)(xcd * 2 + (slot >> 4));
    }
    __syncthreads();
    const int g  = s_g;
    const int ms = s_ms;

    // ---- stage W rows [ms*64,+64) into fragment-order LDS ----
    for (int f = tid; f < MROWS * H / 8; f += 256) {
        const int p   = f >> 6;
        const int l   = f & 63;
        const int kkb = p >> 2;
        const int pwm = (p >> 1) & 1;
        const int prb = p & 1;
        const int pkg = l >> 4;
        const int plm = l & 15;
        const int m = ms * 64 + pwm * 32 + prb * 16 + plm;
        f16x8 v = *(const f16x8*)(Wf + (size_t)m * H + kkb * 32 + pkg * 8);
        *(f16x8*)((char*)Wlds + (size_t)f * 16) = v;
    }
    __syncthreads();   // once, before the loop

    // ---- per-lane constants ----
    const int n      = g * NSLICE + wn * 16 + lm;   // batch column
    const int base32 = ms * 64 + wm * 32;
    float whx0[4], whx1[4];
    #pragma unroll
    for (int r = 0; r < 4; ++r) {
        whx0[r] = Whx[base32 + kg * 4 + r];
        whx1[r] = Whx[base32 + 16 + kg * 4 + r];
    }
    const float bhn = bh[n];

    const ull hu0 = (ull)h0, hu1 = (ull)h1;
    const char* arow = (const char*)Wlds + wm * 2048 + lane * 16;

    // flag block layout: [group][consumer_ms][producer_ms] x 64B lines.
    // I poll MY block (g, ms): lane l -> producer line l&15 (<=1 WG per line).
    // I publish to 16 replicas: lane<16 -> block (g, lane), slot ms.
    const ull fpoll = (ull)(flags +
        (size_t)((((g << 4) | ms) << 4) | (lane & 15)) * FLAG_STRIDE);
    unsigned* fpub = flags +
        (size_t)((((g << 4) | (lane & 15)) << 4) | ms) * FLAG_STRIDE;

    #define COMPUTE8(arr, KB0)                                            \
        _Pragma("unroll")                                                 \
        for (int i = 0; i < 8; ++i) {                                     \
            f16x8 a0 = *(const f16x8*)(arow + (KB0 + i) * 4096);          \
            f16x8 a1 = *(const f16x8*)(arow + (KB0 + i) * 4096 + 1024);   \
            union { u32x4 u; f16x8 v; } bb; bb.u = arr[i];                \
            acc0 = __builtin_amdgcn_mfma_f32_16x16x32_f16(a0, bb.v, acc0, 0, 0, 0); \
            acc1 = __builtin_amdgcn_mfma_f32_16x16x32_f16(a1, bb.v, acc1, 0, 0, 0); \
        }

    for (int t = 0; t < T; ++t) {
        // ---- wait for h(t): backoff sleep, then dual-chain pipelined poll ----
        // Flags commit ~1-1.5us after my own publish (producers are
        // phase-symmetric), so sleeping ~1.3us delays observation by ~0 but
        // removes the futile poll rounds that congest the MALL.
        if (wave == 0 && t) {
            const unsigned tc = (unsigned)t;
            __builtin_amdgcn_s_sleep(48);   // ~3100 cy backoff
            unsigned va, vb;
            PISSUE(va); PISSUE(vb);
            for (;;) {
                asm volatile("s_waitcnt vmcnt(1)" ::: "memory");
                __builtin_amdgcn_sched_barrier(0);
                if (__all((int)(va >= tc))) break;
                PISSUE(va);
                asm volatile("s_waitcnt vmcnt(1)" ::: "memory");
                __builtin_amdgcn_sched_barrier(0);
                if (__all((int)(vb >= tc))) break;
                PISSUE(vb);
            }
            asm volatile("s_waitcnt vmcnt(0)" ::: "memory");  // retire chains
            __builtin_amdgcn_sched_barrier(0);
        }
        __syncthreads();   // release all 4 waves: h(t) readable in L2
        __builtin_amdgcn_sched_barrier(0);

        const ull rdb = (t & 1) ? hu1 : hu0;
        const ull wrb = (t & 1) ? hu0 : hu1;
        const ull rd  = rdb + (size_t)n * 2048 + kg * 16;

        u32x4 hA[8], hB[8];
        f32x4 acc0 = {0.f, 0.f, 0.f, 0.f};
        f32x4 acc1 = {0.f, 0.f, 0.f, 0.f};

        ISSUE8(hA, rd);
        ISSUE8(hB, rd + 512);
        asm volatile("s_waitcnt vmcnt(8)" ::: "memory");
        __builtin_amdgcn_sched_barrier(0);
        COMPUTE8(hA, 0);
        ISSUE8(hA, rd + 1024);
        asm volatile("s_waitcnt vmcnt(8)" ::: "memory");
        __builtin_amdgcn_sched_barrier(0);
        COMPUTE8(hB, 8);
        ISSUE8(hB, rd + 1536);
        asm volatile("s_waitcnt vmcnt(8)" ::: "memory");
        __builtin_amdgcn_sched_barrier(0);
        COMPUTE8(hA, 16);
        asm volatile("s_waitcnt vmcnt(0)" ::: "memory");
        __builtin_amdgcn_sched_barrier(0);
        COMPUTE8(hB, 24);

        // ---- epilogue: rank-1 input + bias + tanh; sc0 stores (-> own L2) ----
        const float xn = xT[(size_t)t * B + n];
        union { ull u; f16x4 v; } s0, s1;
        #pragma unroll
        for (int r = 0; r < 4; ++r)
            s0.v[r] = (_Float16)fast_tanh(acc0[r] + whx0[r] * xn + bhn);
        #pragma unroll
        for (int r = 0; r < 4; ++r)
            s1.v[r] = (_Float16)fast_tanh(acc1[r] + whx1[r] * xn + bhn);
        // h row-major [n][m]: s0 rows at m=base32+kg*4 (8B), s1 at m+16 (+32B)
        const ull wr = wrb + (size_t)n * 2048 + (size_t)(base32 + kg * 4) * 2;
        G_STORE_X2(wr, s0.u);
        G_STORE_X2(wr + 32, s1.u);

        // ---- publish: all waves drained -> wave0 fans out 16 replicas ----
        asm volatile("s_waitcnt vmcnt(0)" ::: "memory");  // reads+stores drained
        __syncthreads();                                  // whole WG drained
        if (wave == 0 && lane < 16)
            __hip_atomic_store(fpub, (unsigned)(t + 1),
                               __ATOMIC_RELAXED, __HIP_MEMORY_SCOPE_AGENT);
        __builtin_amdgcn_sched_barrier(0);
    }
    #undef COMPUTE8
}

// ---- final projection: h plain row-major [B][H] ----
__global__ void proj_kernel(const _Float16* __restrict__ hT,
                            const float* __restrict__ Wph,
                            const float* __restrict__ bp,
                            float* __restrict__ out) {
    const int b = blockIdx.x;
    const int lane = threadIdx.x;  // 64
    float partial[NC];
    #pragma unroll
    for (int c = 0; c < NC; ++c) partial[c] = 0.f;
    for (int i = lane; i < H; i += 64) {
        float hv = (float)hT[(size_t)b * H + i];
        #pragma unroll
        for (int c = 0; c < NC; ++c) partial[c] += Wph[(size_t)c * H + i] * hv;
    }
    #pragma unroll
    for (int c = 0; c < NC; ++c) {
        float v = partial[c];
        #pragma unroll
        for (int off = 32; off; off >>= 1) v += __shfl_down(v, off);
        if (lane == 0) out[(size_t)b * NC + c] = v + bp[b];
    }
}

extern "C" void kernel_launch(void* const* d_in, const int* in_sizes, int n_in,
                              void* d_out, int out_size, void* d_ws, size_t ws_size,
                              hipStream_t stream) {
    const float* x   = (const float*)d_in[0];
    const float* Whx = (const float*)d_in[1];
    const float* Whh = (const float*)d_in[2];
    const float* Wph = (const float*)d_in[3];
    const float* bh  = (const float*)d_in[4];
    const float* bp  = (const float*)d_in[5];
    float* out = (float*)d_out;

    char* ws = (char*)d_ws;
    _Float16* Wf    = (_Float16*)ws;                     // 2 MB
    _Float16* h0    = (_Float16*)(ws + (2u << 20));      // 1 MB
    _Float16* h1    = (_Float16*)(ws + (3u << 20));      // 1 MB
    float*    xT    = (float*)(ws + (4u << 20));         // 1 MB
    unsigned* flags = (unsigned*)(ws + (5u << 20));      // 16*16*16 x 64B = 256 KB
    unsigned* claim = (unsigned*)(ws + (5u << 20) + 262144);

    convert_w<<<(H * H / 4) / 256, 256, 0, stream>>>(Whh, Wf);
    transpose_x<<<dim3(T / 32, B / 32), 256, 0, stream>>>(x, xT);
    hipMemsetAsync(h0, 0, (size_t)B * H * 2, stream);
    hipMemsetAsync(flags, 0, 262144 + 256, stream);

    rnn_persist<<<NGROUPS * WPG, 256, 0, stream>>>(Wf, xT, Whx, bh,
                                                   h0, h1, flags, claim);

    // T even -> final h in h0
    proj_kernel<<<B, 64, 0, stream>>>(h0, Wph, bp, out);
}

// Round 16
// 2962.187 us; speedup vs baseline: 1.0344x; 1.0344x over previous
//
#include <hip/hip_runtime.h>
#include <hip/hip_fp16.h>

#define H 1024
#define B 512
#define T 512
#define NC 10

#define NGROUPS 16      // batch-slice groups (32 batches each)
#define WPG 16          // WGs per group (M slices)
#define NSLICE 32       // batches per group
#define MROWS 64        // H rows per WG
#define FLAG_STRIDE 16  // 16 u32 = 64B per flag line

typedef _Float16 f16x8 __attribute__((ext_vector_type(8)));
typedef _Float16 f16x4 __attribute__((ext_vector_type(4)));
typedef float    f32x4 __attribute__((ext_vector_type(4)));
typedef unsigned u32x4 __attribute__((ext_vector_type(4)));
typedef unsigned long long ull;

__device__ __forceinline__ float fast_tanh(float x) {
    float e = __expf(2.0f * x);
    return 1.0f - 2.0f / (e + 1.0f);
}

// ---- W_hh f32 -> f16 row-major ----
__global__ void convert_w(const float* __restrict__ w, _Float16* __restrict__ o) {
    int i = (blockIdx.x * 256 + threadIdx.x) * 4;
    float4 v = *(const float4*)(w + i);
    f16x4 r;
    r[0] = (_Float16)v.x; r[1] = (_Float16)v.y;
    r[2] = (_Float16)v.z; r[3] = (_Float16)v.w;
    *(f16x4*)(o + i) = r;
}

// ---- x [B][T] -> xT [T][B] ----
__global__ void transpose_x(const float* __restrict__ x, float* __restrict__ xT) {
    __shared__ float tile[32][33];
    const int tx = threadIdx.x & 31;
    const int ty = threadIdx.x >> 5;
    const int t0 = blockIdx.x * 32;
    const int b0 = blockIdx.y * 32;
    #pragma unroll
    for (int i = ty; i < 32; i += 8)
        tile[i][tx] = x[(size_t)(b0 + i) * T + t0 + tx];
    __syncthreads();
    #pragma unroll
    for (int i = ty; i < 32; i += 8)
        xT[(size_t)(t0 + i) * B + b0 + tx] = tile[tx][i];
}

// h load: sc0 only -> bypass own stale L1, served by the XCD-shared L2
#define G_LOAD_X4(dst, addr, OFF) \
    asm volatile("global_load_dwordx4 %0, %1, off offset:" OFF " sc0" \
                 : "=&v"(dst) : "v"(addr) : "memory")

#define ISSUE8(arr, base) do { \
    G_LOAD_X4(arr[0], (base), "0");   G_LOAD_X4(arr[1], (base), "64");  \
    G_LOAD_X4(arr[2], (base), "128"); G_LOAD_X4(arr[3], (base), "192"); \
    G_LOAD_X4(arr[4], (base), "256"); G_LOAD_X4(arr[5], (base), "320"); \
    G_LOAD_X4(arr[6], (base), "384"); G_LOAD_X4(arr[7], (base), "448"); \
} while (0)

// h store: sc0 -> coherent write-through to the XCD-shared L2 (stops at L2)
#define G_STORE_X2(addr, data) \
    asm volatile("global_store_dwordx2 %0, %1, off sc0" \
                 :: "v"(addr), "v"(data) : "memory")

// flag poll: agent-scope load (MALL) — proven prompt-visibility path
#define PISSUE(v) \
    asm volatile("global_load_dword %0, %1, off sc0 sc1" \
                 : "=&v"(v) : "v"(fpoll) : "memory")

// ---- persistent RNN: 256 WGs x 256 thr (4 waves) ----
// R13 sync protocol verbatim (replicated MALL flags, wave0 dual-chain poll,
// syncthreads release). Compute-side changes only:
//  (1) 32-deep h-load pipeline with counted vmcnt(24/16/8/0) — only the
//      first wait pays the L2 RTT;
//  (2) xT load hoisted above the pipeline;
//  (3) earliest-publish: LDS arrival counter, LAST wave publishes (its
//      ds_add observing old==4t+3 certifies all waves' vmcnt(0) drains).
__global__ void __launch_bounds__(256, 1) rnn_persist(
        const _Float16* __restrict__ Wf, const float* __restrict__ xT,
        const float* __restrict__ Whx, const float* __restrict__ bh,
        _Float16* h0, _Float16* h1, unsigned* flags, unsigned* claim) {

    __shared__ _Float16 Wlds[MROWS * H];   // 128 KB -> exactly 1 WG/CU
    __shared__ int s_g, s_ms;
    __shared__ unsigned s_cnt;

    const int tid  = threadIdx.x;
    const int wave = tid >> 6;
    const int lane = tid & 63;
    const int lm   = lane & 15;
    const int kg   = lane >> 4;
    const int wm   = wave >> 1;            // M half 0..1
    const int wn   = wave & 1;             // N half 0..1

    // ---- dynamic XCD grouping (capacity-forced: exactly 32 WGs per XCD) ----
    if (tid == 0) {
        unsigned xcd;
        asm volatile("s_getreg_b32 %0, hwreg(HW_REG_XCC_ID)" : "=s"(xcd));
        xcd &= 7;
        unsigned slot = atomicAdd(&claim[xcd], 1u);   // 0..31 per XCD
        s_ms = (int)(slot & 15);
        s_g  = (int)(xcd * 2 + (slot >> 4));
        s_cnt = 0;
    }
    __syncthreads();
    const int g  = s_g;
    const int ms = s_ms;

    // ---- stage W rows [ms*64,+64) into fragment-order LDS ----
    for (int f = tid; f < MROWS * H / 8; f += 256) {
        const int p   = f >> 6;
        const int l   = f & 63;
        const int kkb = p >> 2;
        const int pwm = (p >> 1) & 1;
        const int prb = p & 1;
        const int pkg = l >> 4;
        const int plm = l & 15;
        const int m = ms * 64 + pwm * 32 + prb * 16 + plm;
        f16x8 v = *(const f16x8*)(Wf + (size_t)m * H + kkb * 32 + pkg * 8);
        *(f16x8*)((char*)Wlds + (size_t)f * 16) = v;
    }
    __syncthreads();   // once, before the loop

    // ---- per-lane constants ----
    const int n      = g * NSLICE + wn * 16 + lm;   // batch column
    const int base32 = ms * 64 + wm * 32;
    float whx0[4], whx1[4];
    #pragma unroll
    for (int r = 0; r < 4; ++r) {
        whx0[r] = Whx[base32 + kg * 4 + r];
        whx1[r] = Whx[base32 + 16 + kg * 4 + r];
    }
    const float bhn = bh[n];

    const ull hu0 = (ull)h0, hu1 = (ull)h1;
    const char* arow = (const char*)Wlds + wm * 2048 + lane * 16;

    // flag block layout: [group][consumer_ms][producer_ms] x 64B lines.
    // I poll MY block (g, ms): lane l -> producer line l&15 (<=1 WG per line).
    // I publish to 16 replicas: lane<16 -> block (g, lane), slot ms.
    const ull fpoll = (ull)(flags +
        (size_t)((((g << 4) | ms) << 4) | (lane & 15)) * FLAG_STRIDE);
    unsigned* fpub = flags +
        (size_t)((((g << 4) | (lane & 15)) << 4) | ms) * FLAG_STRIDE;

    #define COMPUTE8(arr, KB0)                                            \
        _Pragma("unroll")                                                 \
        for (int i = 0; i < 8; ++i) {                                     \
            f16x8 a0 = *(const f16x8*)(arow + (KB0 + i) * 4096);          \
            f16x8 a1 = *(const f16x8*)(arow + (KB0 + i) * 4096 + 1024);   \
            union { u32x4 u; f16x8 v; } bb; bb.u = arr[i];                \
            acc0 = __builtin_amdgcn_mfma_f32_16x16x32_f16(a0, bb.v, acc0, 0, 0, 0); \
            acc1 = __builtin_amdgcn_mfma_f32_16x16x32_f16(a1, bb.v, acc1, 0, 0, 0); \
        }

    for (int t = 0; t < T; ++t) {
        // ---- wait for h(t): wave0 dual-chain pipelined poll (R13-proven) ----
        if (wave == 0 && t) {
            const unsigned tc = (unsigned)t;
            unsigned va, vb;
            PISSUE(va); PISSUE(vb);
            for (;;) {
                asm volatile("s_waitcnt vmcnt(1)" ::: "memory");
                __builtin_amdgcn_sched_barrier(0);
                if (__all((int)(va >= tc))) break;
                PISSUE(va);
                asm volatile("s_waitcnt vmcnt(1)" ::: "memory");
                __builtin_amdgcn_sched_barrier(0);
                if (__all((int)(vb >= tc))) break;
                PISSUE(vb);
            }
            asm volatile("s_waitcnt vmcnt(0)" ::: "memory");  // retire chains
            __builtin_amdgcn_sched_barrier(0);
        }
        __syncthreads();   // release all 4 waves: h(t) readable in L2
        __builtin_amdgcn_sched_barrier(0);

        const ull rdb = (t & 1) ? hu1 : hu0;
        const ull wrb = (t & 1) ? hu0 : hu1;
        const ull rd  = rdb + (size_t)n * 2048 + kg * 16;

        // xT load hoisted: oldest outstanding, retires with the first 8.
        const float xn = xT[(size_t)t * B + n];

        u32x4 hA[8], hB[8], hC[8], hD[8];
        f32x4 acc0 = {0.f, 0.f, 0.f, 0.f};
        f32x4 acc1 = {0.f, 0.f, 0.f, 0.f};

        // ---- 32-deep pipeline: issue everything, drain with counted waits ----
        ISSUE8(hA, rd);
        ISSUE8(hB, rd + 512);
        ISSUE8(hC, rd + 1024);
        ISSUE8(hD, rd + 1536);
        asm volatile("s_waitcnt vmcnt(24)" ::: "memory");
        __builtin_amdgcn_sched_barrier(0);
        COMPUTE8(hA, 0);
        asm volatile("s_waitcnt vmcnt(16)" ::: "memory");
        __builtin_amdgcn_sched_barrier(0);
        COMPUTE8(hB, 8);
        asm volatile("s_waitcnt vmcnt(8)" ::: "memory");
        __builtin_amdgcn_sched_barrier(0);
        COMPUTE8(hC, 16);
        asm volatile("s_waitcnt vmcnt(0)" ::: "memory");
        __builtin_amdgcn_sched_barrier(0);
        COMPUTE8(hD, 24);

        // ---- epilogue: rank-1 input + bias + tanh; sc0 stores (-> own L2) ----
        union { ull u; f16x4 v; } s0, s1;
        #pragma unroll
        for (int r = 0; r < 4; ++r)
            s0.v[r] = (_Float16)fast_tanh(acc0[r] + whx0[r] * xn + bhn);
        #pragma unroll
        for (int r = 0; r < 4; ++r)
            s1.v[r] = (_Float16)fast_tanh(acc1[r] + whx1[r] * xn + bhn);
        // h row-major [n][m]: s0 rows at m=base32+kg*4 (8B), s1 at m+16 (+32B)
        const ull wr = wrb + (size_t)n * 2048 + (size_t)(base32 + kg * 4) * 2;
        G_STORE_X2(wr, s0.u);
        G_STORE_X2(wr + 32, s1.u);

        // ---- earliest publish: last-arriving wave fans out 16 replicas ----
        asm volatile("s_waitcnt vmcnt(0)" ::: "memory");  // my stores in L2
        unsigned old = 0;
        if (lane == 0)
            old = __hip_atomic_fetch_add(&s_cnt, 1u, __ATOMIC_RELAXED,
                                         __HIP_MEMORY_SCOPE_WORKGROUP);
        old = __shfl(old, 0);
        // old == 4t+3 => the other 3 waves already did vmcnt(0) + ds_add
        // => ALL h(t+1) stores of this WG are in L2 => safe to certify.
        if (old == (unsigned)(4 * t + 3) && lane < 16)
            __hip_atomic_store(fpub, (unsigned)(t + 1),
                               __ATOMIC_RELAXED, __HIP_MEMORY_SCOPE_AGENT);
        __builtin_amdgcn_sched_barrier(0);
    }
    #undef COMPUTE8
}

// ---- final projection: h plain row-major [B][H] ----
__global__ void proj_kernel(const _Float16* __restrict__ hT,
                            const float* __restrict__ Wph,
                            const float* __restrict__ bp,
                            float* __restrict__ out) {
    const int b = blockIdx.x;
    const int lane = threadIdx.x;  // 64
    float partial[NC];
    #pragma unroll
    for (int c = 0; c < NC; ++c) partial[c] = 0.f;
    for (int i = lane; i < H; i += 64) {
        float hv = (float)hT[(size_t)b * H + i];
        #pragma unroll
        for (int c = 0; c < NC; ++c) partial[c] += Wph[(size_t)c * H + i] * hv;
    }
    #pragma unroll
    for (int c = 0; c < NC; ++c) {
        float v = partial[c];
        #pragma unroll
        for (int off = 32; off; off >>= 1) v += __shfl_down(v, off);
        if (lane == 0) out[(size_t)b * NC + c] = v + bp[b];
    }
}

extern "C" void kernel_launch(void* const* d_in, const int* in_sizes, int n_in,
                              void* d_out, int out_size, void* d_ws, size_t ws_size,
                              hipStream_t stream) {
    const float* x   = (const float*)d_in[0];
    const float* Whx = (const float*)d_in[1];
    const float* Whh = (const float*)d_in[2];
    const float* Wph = (const float*)d_in[3];
    const float* bh  = (const float*)d_in[4];
    const float* bp  = (const float*)d_in[5];
    float* out = (float*)d_out;

    char* ws = (char*)d_ws;
    _Float16* Wf    = (_Float16*)ws;                     // 2 MB
    _Float16* h0    = (_Float16*)(ws + (2u << 20));      // 1 MB
    _Float16* h1    = (_Float16*)(ws + (3u << 20));      // 1 MB
    float*    xT    = (float*)(ws + (4u << 20));         // 1 MB
    unsigned* flags = (unsigned*)(ws + (5u << 20));      // 16*16*16 x 64B = 256 KB
    unsigned* claim = (unsigned*)(ws + (5u << 20) + 262144);

    convert_w<<<(H * H / 4) / 256, 256, 0, stream>>>(Whh, Wf);
    transpose_x<<<dim3(T / 32, B / 32), 256, 0, stream>>>(x, xT);
    hipMemsetAsync(h0, 0, (size_t)B * H * 2, stream);
    hipMemsetAsync(flags, 0, 262144 + 256, stream);

    rnn_persist<<<NGROUPS * WPG, 256, 0, stream>>>(Wf, xT, Whx, bh,
                                                   h0, h1, flags, claim);

    // T even -> final h in h0
    proj_kernel<<<B, 64, 0, stream>>>(h0, Wph, bp, out);
}

// Round 17
// 2140.129 us; speedup vs baseline: 1.4317x; 1.3841x over previous
//
#include <hip/hip_runtime.h>
#include <hip/hip_fp16.h>

#define H 1024
#define B 512
#define T 512
#define NC 10

#define NGROUPS 16      // batch-slice groups (32 batches each)
#define WPG 16          // WGs per group (M slices)
#define NSLICE 32       // batches per group
#define MROWS 64        // H rows per WG
#define FLAG_STRIDE 16  // 16 u32 = 64B per flag line
#define NT 512          // 8 waves per WG

typedef _Float16 f16x8 __attribute__((ext_vector_type(8)));
typedef _Float16 f16x4 __attribute__((ext_vector_type(4)));
typedef float    f32x4 __attribute__((ext_vector_type(4)));
typedef unsigned u32x4 __attribute__((ext_vector_type(4)));
typedef unsigned long long ull;

__device__ __forceinline__ float fast_tanh(float x) {
    float e = __expf(2.0f * x);
    return 1.0f - 2.0f / (e + 1.0f);
}

// ---- W_hh f32 -> f16 row-major ----
__global__ void convert_w(const float* __restrict__ w, _Float16* __restrict__ o) {
    int i = (blockIdx.x * 256 + threadIdx.x) * 4;
    float4 v = *(const float4*)(w + i);
    f16x4 r;
    r[0] = (_Float16)v.x; r[1] = (_Float16)v.y;
    r[2] = (_Float16)v.z; r[3] = (_Float16)v.w;
    *(f16x4*)(o + i) = r;
}

// ---- x [B][T] -> xT [T][B] ----
__global__ void transpose_x(const float* __restrict__ x, float* __restrict__ xT) {
    __shared__ float tile[32][33];
    const int tx = threadIdx.x & 31;
    const int ty = threadIdx.x >> 5;
    const int t0 = blockIdx.x * 32;
    const int b0 = blockIdx.y * 32;
    #pragma unroll
    for (int i = ty; i < 32; i += 8)
        tile[i][tx] = x[(size_t)(b0 + i) * T + t0 + tx];
    __syncthreads();
    #pragma unroll
    for (int i = ty; i < 32; i += 8)
        xT[(size_t)(t0 + i) * B + b0 + tx] = tile[tx][i];
}

// h load: sc0 only -> bypass own stale L1, served by the XCD-shared L2
#define G_LOAD_X4(dst, addr, OFF) \
    asm volatile("global_load_dwordx4 %0, %1, off offset:" OFF " sc0" \
                 : "=&v"(dst) : "v"(addr) : "memory")

#define ISSUE8(arr, base) do { \
    G_LOAD_X4(arr[0], (base), "0");   G_LOAD_X4(arr[1], (base), "64");  \
    G_LOAD_X4(arr[2], (base), "128"); G_LOAD_X4(arr[3], (base), "192"); \
    G_LOAD_X4(arr[4], (base), "256"); G_LOAD_X4(arr[5], (base), "320"); \
    G_LOAD_X4(arr[6], (base), "384"); G_LOAD_X4(arr[7], (base), "448"); \
} while (0)

// h store: sc0 -> coherent write-through to the XCD-shared L2 (stops at L2)
#define G_STORE_X2(addr, data) \
    asm volatile("global_store_dwordx2 %0, %1, off sc0" \
                 :: "v"(addr), "v"(data) : "memory")

// flag poll: agent-scope load (MALL) — proven prompt-visibility path
#define PISSUE(v) \
    asm volatile("global_load_dword %0, %1, off sc0 sc1" \
                 : "=&v"(v) : "v"(fpoll) : "memory")

// ---- persistent RNN: 256 WGs x 512 thr (8 waves), K-split ----
// Sync protocol = R13 verbatim. Compute restructured for TLP:
// wave (wk 0..3, wn 0..1): partial GEMM over K-chunk [wk*256,+256) for all
// 64 rows x 16 batches (4 accs). 2 waves/SIMD hide load latency in HW.
// wk=1..3 write partials to LDS; wk=0 waves reduce + tanh + sc0-store.
__global__ void __launch_bounds__(NT, 1) rnn_persist(
        const _Float16* __restrict__ Wf, const float* __restrict__ xT,
        const float* __restrict__ Whx, const float* __restrict__ bh,
        _Float16* h0, _Float16* h1, unsigned* flags, unsigned* claim) {

    __shared__ _Float16 Wlds[MROWS * H];    // 128 KB
    __shared__ f32x4 red[6][4][64];         // 24 KB: [(wk-1)*2+wn][mf][lane]
    __shared__ int s_g, s_ms;               // -> 152 KB total, 1 WG/CU

    const int tid  = threadIdx.x;
    const int wave = tid >> 6;     // 0..7
    const int lane = tid & 63;
    const int lm   = lane & 15;
    const int kg   = lane >> 4;
    const int wk   = wave >> 1;    // K quarter 0..3
    const int wn   = wave & 1;     // batch half 0..1

    // ---- dynamic XCD grouping (capacity-forced: exactly 32 WGs per XCD) ----
    if (tid == 0) {
        unsigned xcd;
        asm volatile("s_getreg_b32 %0, hwreg(HW_REG_XCC_ID)" : "=s"(xcd));
        xcd &= 7;
        unsigned slot = atomicAdd(&claim[xcd], 1u);   // 0..31 per XCD
        s_ms = (int)(slot & 15);
        s_g  = (int)(xcd * 2 + (slot >> 4));
    }
    __syncthreads();
    const int g  = s_g;
    const int ms = s_ms;

    // ---- stage W rows [ms*64,+64) into fragment-order LDS ----
    for (int f = tid; f < MROWS * H / 8; f += NT) {
        const int p   = f >> 6;
        const int l   = f & 63;
        const int kkb = p >> 2;
        const int pwm = (p >> 1) & 1;
        const int prb = p & 1;
        const int pkg = l >> 4;
        const int plm = l & 15;
        const int m = ms * 64 + pwm * 32 + prb * 16 + plm;
        f16x8 v = *(const f16x8*)(Wf + (size_t)m * H + kkb * 32 + pkg * 8);
        *(f16x8*)((char*)Wlds + (size_t)f * 16) = v;
    }
    __syncthreads();   // once, before the loop

    // ---- per-lane constants ----
    const int n = g * NSLICE + wn * 16 + lm;   // batch column
    float whx[4][4];   // all 4 M-frags (used by wk=0 epilogue)
    #pragma unroll
    for (int mf = 0; mf < 4; ++mf)
        #pragma unroll
        for (int r = 0; r < 4; ++r)
            whx[mf][r] = Whx[ms * 64 + (mf >> 1) * 32 + (mf & 1) * 16 + kg * 4 + r];
    const float bhn = bh[n];

    const ull hu0 = (ull)h0, hu1 = (ull)h1;
    // A-frag base for my K quarter: kb local 0..7 at abase + kb*4096 + mf*1024
    const char* abase = (const char*)Wlds + (size_t)wk * 32768 + lane * 16;

    // flag block layout (R13): [group][consumer_ms][producer_ms] x 64B lines.
    const ull fpoll = (ull)(flags +
        (size_t)((((g << 4) | ms) << 4) | (lane & 15)) * FLAG_STRIDE);
    unsigned* fpub = flags +
        (size_t)((((g << 4) | (lane & 15)) << 4) | ms) * FLAG_STRIDE;

    #define KSTEP(KB, CNT) do {                                               \
        asm volatile("s_waitcnt vmcnt(" CNT ")" ::: "memory");                \
        __builtin_amdgcn_sched_barrier(0);                                    \
        f16x8 a0 = *(const f16x8*)(abase + KB * 4096);                        \
        f16x8 a1 = *(const f16x8*)(abase + KB * 4096 + 1024);                 \
        f16x8 a2 = *(const f16x8*)(abase + KB * 4096 + 2048);                 \
        f16x8 a3 = *(const f16x8*)(abase + KB * 4096 + 3072);                 \
        union { u32x4 u; f16x8 v; } bb; bb.u = hB[KB];                        \
        acc0 = __builtin_amdgcn_mfma_f32_16x16x32_f16(a0, bb.v, acc0, 0,0,0); \
        acc1 = __builtin_amdgcn_mfma_f32_16x16x32_f16(a1, bb.v, acc1, 0,0,0); \
        acc2 = __builtin_amdgcn_mfma_f32_16x16x32_f16(a2, bb.v, acc2, 0,0,0); \
        acc3 = __builtin_amdgcn_mfma_f32_16x16x32_f16(a3, bb.v, acc3, 0,0,0); \
    } while (0)

    #define EPI(ACC, MF, OFF) do {                                            \
        union { ull u; f16x4 v; } s_;                                         \
        _Pragma("unroll")                                                     \
        for (int r = 0; r < 4; ++r)                                           \
            s_.v[r] = (_Float16)fast_tanh(ACC[r] + whx[MF][r] * xn + bhn);    \
        G_STORE_X2(wr + OFF, s_.u);                                           \
    } while (0)

    for (int t = 0; t < T; ++t) {
        // ---- wait for h(t): wave0 dual-chain pipelined poll (R13-proven) ----
        if (wave == 0 && t) {
            const unsigned tc = (unsigned)t;
            unsigned va, vb;
            PISSUE(va); PISSUE(vb);
            for (;;) {
                asm volatile("s_waitcnt vmcnt(1)" ::: "memory");
                __builtin_amdgcn_sched_barrier(0);
                if (__all((int)(va >= tc))) break;
                PISSUE(va);
                asm volatile("s_waitcnt vmcnt(1)" ::: "memory");
                __builtin_amdgcn_sched_barrier(0);
                if (__all((int)(vb >= tc))) break;
                PISSUE(vb);
            }
            asm volatile("s_waitcnt vmcnt(0)" ::: "memory");  // retire chains
            __builtin_amdgcn_sched_barrier(0);
        }
        __syncthreads();   // (a) release all 8 waves: h(t) readable in L2
        __builtin_amdgcn_sched_barrier(0);

        const ull rdb = (t & 1) ? hu1 : hu0;
        const ull wrb = (t & 1) ? hu0 : hu1;
        const ull rd  = rdb + (size_t)n * 2048 + wk * 512 + kg * 16;

        u32x4 hB[8];
        f32x4 acc0 = {0.f, 0.f, 0.f, 0.f};
        f32x4 acc1 = {0.f, 0.f, 0.f, 0.f};
        f32x4 acc2 = {0.f, 0.f, 0.f, 0.f};
        f32x4 acc3 = {0.f, 0.f, 0.f, 0.f};

        ISSUE8(hB, rd);
        KSTEP(0, "7"); KSTEP(1, "6"); KSTEP(2, "5"); KSTEP(3, "4");
        KSTEP(4, "3"); KSTEP(5, "2"); KSTEP(6, "1"); KSTEP(7, "0");

        if (wk) {   // publish partials to LDS
            const int ri = (wk - 1) * 2 + wn;
            red[ri][0][lane] = acc0;
            red[ri][1][lane] = acc1;
            red[ri][2][lane] = acc2;
            red[ri][3][lane] = acc3;
        }
        __syncthreads();   // (b) partials visible

        if (wk == 0) {
            const float xn = xT[(size_t)t * B + n];
            #pragma unroll
            for (int j = 0; j < 3; ++j) {
                const int ri = j * 2 + wn;
                acc0 += red[ri][0][lane];
                acc1 += red[ri][1][lane];
                acc2 += red[ri][2][lane];
                acc3 += red[ri][3][lane];
            }
            // h row-major [n][m]: mf stores at +0/32/64/96 bytes
            const ull wr = wrb + (size_t)n * 2048 + (size_t)(ms * 128) + kg * 8;
            EPI(acc0, 0, 0);
            EPI(acc1, 1, 32);
            EPI(acc2, 2, 64);
            EPI(acc3, 3, 96);
            asm volatile("s_waitcnt vmcnt(0)" ::: "memory");  // stores in L2
        }
        __syncthreads();   // (c) whole WG drained (incl. wk=0 stores)
        if (wave == 0 && lane < 16)
            __hip_atomic_store(fpub, (unsigned)(t + 1),
                               __ATOMIC_RELAXED, __HIP_MEMORY_SCOPE_AGENT);
        __builtin_amdgcn_sched_barrier(0);
    }
    #undef KSTEP
    #undef EPI
}

// ---- final projection: h plain row-major [B][H] ----
__global__ void proj_kernel(const _Float16* __restrict__ hT,
                            const float* __restrict__ Wph,
                            const float* __restrict__ bp,
                            float* __restrict__ out) {
    const int b = blockIdx.x;
    const int lane = threadIdx.x;  // 64
    float partial[NC];
    #pragma unroll
    for (int c = 0; c < NC; ++c) partial[c] = 0.f;
    for (int i = lane; i < H; i += 64) {
        float hv = (float)hT[(size_t)b * H + i];
        #pragma unroll
        for (int c = 0; c < NC; ++c) partial[c] += Wph[(size_t)c * H + i] * hv;
    }
    #pragma unroll
    for (int c = 0; c < NC; ++c) {
        float v = partial[c];
        #pragma unroll
        for (int off = 32; off; off >>= 1) v += __shfl_down(v, off);
        if (lane == 0) out[(size_t)b * NC + c] = v + bp[b];
    }
}

extern "C" void kernel_launch(void* const* d_in, const int* in_sizes, int n_in,
                              void* d_out, int out_size, void* d_ws, size_t ws_size,
                              hipStream_t stream) {
    const float* x   = (const float*)d_in[0];
    const float* Whx = (const float*)d_in[1];
    const float* Whh = (const float*)d_in[2];
    const float* Wph = (const float*)d_in[3];
    const float* bh  = (const float*)d_in[4];
    const float* bp  = (const float*)d_in[5];
    float* out = (float*)d_out;

    char* ws = (char*)d_ws;
    _Float16* Wf    = (_Float16*)ws;                     // 2 MB
    _Float16* h0    = (_Float16*)(ws + (2u << 20));      // 1 MB
    _Float16* h1    = (_Float16*)(ws + (3u << 20));      // 1 MB
    float*    xT    = (float*)(ws + (4u << 20));         // 1 MB
    unsigned* flags = (unsigned*)(ws + (5u << 20));      // 256 KB
    unsigned* claim = (unsigned*)(ws + (5u << 20) + 262144);

    convert_w<<<(H * H / 4) / 256, 256, 0, stream>>>(Whh, Wf);
    transpose_x<<<dim3(T / 32, B / 32), 256, 0, stream>>>(x, xT);
    hipMemsetAsync(h0, 0, (size_t)B * H * 2, stream);
    hipMemsetAsync(flags, 0, 262144 + 256, stream);

    rnn_persist<<<NGROUPS * WPG, NT, 0, stream>>>(Wf, xT, Whx, bh,
                                                  h0, h1, flags, claim);

    // T even -> final h in h0
    proj_kernel<<<B, 64, 0, stream>>>(h0, Wph, bp, out);
}

// Round 18
// 2064.676 us; speedup vs baseline: 1.4840x; 1.0365x over previous
//
#include <hip/hip_runtime.h>
#include <hip/hip_fp16.h>

#define H 1024
#define B 512
#define T 512
#define NC 10

#define NGROUPS 16      // batch-slice groups (32 batches each)
#define WPG 16          // WGs per group (M slices)
#define NSLICE 32       // batches per group
#define MROWS 64        // H rows per WG
#define FLAG_STRIDE 16  // 16 u32 = 64B per flag line
#define NT 512          // 8 waves per WG

typedef _Float16 f16x8 __attribute__((ext_vector_type(8)));
typedef _Float16 f16x4 __attribute__((ext_vector_type(4)));
typedef float    f32x4 __attribute__((ext_vector_type(4)));
typedef unsigned u32x4 __attribute__((ext_vector_type(4)));
typedef unsigned long long ull;

__device__ __forceinline__ float fast_tanh(float x) {
    float e = __expf(2.0f * x);
    return 1.0f - 2.0f / (e + 1.0f);
}

// ---- W_hh f32 -> f16 row-major ----
__global__ void convert_w(const float* __restrict__ w, _Float16* __restrict__ o) {
    int i = (blockIdx.x * 256 + threadIdx.x) * 4;
    float4 v = *(const float4*)(w + i);
    f16x4 r;
    r[0] = (_Float16)v.x; r[1] = (_Float16)v.y;
    r[2] = (_Float16)v.z; r[3] = (_Float16)v.w;
    *(f16x4*)(o + i) = r;
}

// ---- x [B][T] -> xT [T][B] ----
__global__ void transpose_x(const float* __restrict__ x, float* __restrict__ xT) {
    __shared__ float tile[32][33];
    const int tx = threadIdx.x & 31;
    const int ty = threadIdx.x >> 5;
    const int t0 = blockIdx.x * 32;
    const int b0 = blockIdx.y * 32;
    #pragma unroll
    for (int i = ty; i < 32; i += 8)
        tile[i][tx] = x[(size_t)(b0 + i) * T + t0 + tx];
    __syncthreads();
    #pragma unroll
    for (int i = ty; i < 32; i += 8)
        xT[(size_t)(t0 + i) * B + b0 + tx] = tile[tx][i];
}

// h load: sc0 only -> bypass own stale L1, served by the XCD-shared L2
#define G_LOAD_X4(dst, addr, OFF) \
    asm volatile("global_load_dwordx4 %0, %1, off offset:" OFF " sc0" \
                 : "=&v"(dst) : "v"(addr) : "memory")

#define ISSUE8(arr, base) do { \
    G_LOAD_X4(arr[0], (base), "0");   G_LOAD_X4(arr[1], (base), "64");  \
    G_LOAD_X4(arr[2], (base), "128"); G_LOAD_X4(arr[3], (base), "192"); \
    G_LOAD_X4(arr[4], (base), "256"); G_LOAD_X4(arr[5], (base), "320"); \
    G_LOAD_X4(arr[6], (base), "384"); G_LOAD_X4(arr[7], (base), "448"); \
} while (0)

// h store: sc0 -> coherent write-through to the XCD-shared L2 (stops at L2)
#define G_STORE_X2(addr, data) \
    asm volatile("global_store_dwordx2 %0, %1, off sc0" \
                 :: "v"(addr), "v"(data) : "memory")

// flag poll: agent-scope load (MALL) — proven prompt-visibility path
#define PISSUE(v) \
    asm volatile("global_load_dword %0, %1, off sc0 sc1" \
                 : "=&v"(v) : "v"(fpoll) : "memory")

// ---- persistent RNN: 256 WGs x 512 thr (8 waves), K-split ----
// vs R17 (proven): (1) per-wave fine-grained poll — wave (wk,wn) waits only
// on its 4 K-chunk producers (max-of-4, not max-of-16); sync(a) deleted.
// Writes still occur after sync(b), where the union of all waves' polls
// certifies all 16 flags >= t (same write-after-read invariant as R13/R17).
// (2) distributed epilogue — wave (wk,wn) reduces fragment mf=wk (3 ds_reads
// + 4 tanh + 1 store per lane instead of wk0-waves doing 4x that serially).
__global__ void __launch_bounds__(NT, 1) rnn_persist(
        const _Float16* __restrict__ Wf, const float* __restrict__ xT,
        const float* __restrict__ Whx, const float* __restrict__ bh,
        _Float16* h0, _Float16* h1, unsigned* flags, unsigned* claim) {

    __shared__ _Float16 Wlds[MROWS * H];    // 128 KB
    __shared__ f32x4 red[12][2][64];        // 24 KB (diagonal-compacted)
    __shared__ int s_g, s_ms;               // -> 152 KB total, 1 WG/CU

    const int tid  = threadIdx.x;
    const int wave = tid >> 6;     // 0..7
    const int lane = tid & 63;
    const int lm   = lane & 15;
    const int kg   = lane >> 4;
    const int wk   = wave >> 1;    // K quarter 0..3
    const int wn   = wave & 1;     // batch half 0..1

    // ---- dynamic XCD grouping (capacity-forced: exactly 32 WGs per XCD) ----
    if (tid == 0) {
        unsigned xcd;
        asm volatile("s_getreg_b32 %0, hwreg(HW_REG_XCC_ID)" : "=s"(xcd));
        xcd &= 7;
        unsigned slot = atomicAdd(&claim[xcd], 1u);   // 0..31 per XCD
        s_ms = (int)(slot & 15);
        s_g  = (int)(xcd * 2 + (slot >> 4));
    }
    __syncthreads();
    const int g  = s_g;
    const int ms = s_ms;

    // ---- stage W rows [ms*64,+64) into fragment-order LDS ----
    for (int f = tid; f < MROWS * H / 8; f += NT) {
        const int p   = f >> 6;
        const int l   = f & 63;
        const int kkb = p >> 2;
        const int pwm = (p >> 1) & 1;
        const int prb = p & 1;
        const int pkg = l >> 4;
        const int plm = l & 15;
        const int m = ms * 64 + pwm * 32 + prb * 16 + plm;
        f16x8 v = *(const f16x8*)(Wf + (size_t)m * H + kkb * 32 + pkg * 8);
        *(f16x8*)((char*)Wlds + (size_t)f * 16) = v;
    }
    __syncthreads();   // once, before the loop

    // ---- per-lane constants ----
    const int n = g * NSLICE + wn * 16 + lm;   // batch column
    // Whx for MY output fragment mf = wk only
    float whxm[4];
    #pragma unroll
    for (int r = 0; r < 4; ++r)
        whxm[r] = Whx[ms * 64 + (wk >> 1) * 32 + (wk & 1) * 16 + kg * 4 + r];
    const float bhn = bh[n];

    const ull hu0 = (ull)h0, hu1 = (ull)h1;
    // A-frag base for my K quarter
    const char* abase = (const char*)Wlds + (size_t)wk * 32768 + lane * 16;

    // flag block layout (R13): [group][consumer_ms][producer_ms] x 64B lines.
    // Fine-grained: wave (wk,wn) polls ONLY producers 4wk..4wk+3
    // (lane l -> line 4wk + (l&3); 16 lanes/line coalesce to 1 request).
    const ull fpoll = (ull)(flags +
        (size_t)((((g << 4) | ms) << 4) | (wk * 4 + (lane & 3))) * FLAG_STRIDE);
    unsigned* fpub = flags +
        (size_t)((((g << 4) | (lane & 15)) << 4) | ms) * FLAG_STRIDE;

    #define KSTEP(KB, CNT) do {                                               \
        asm volatile("s_waitcnt vmcnt(" CNT ")" ::: "memory");                \
        __builtin_amdgcn_sched_barrier(0);                                    \
        f16x8 a0 = *(const f16x8*)(abase + KB * 4096);                        \
        f16x8 a1 = *(const f16x8*)(abase + KB * 4096 + 1024);                 \
        f16x8 a2 = *(const f16x8*)(abase + KB * 4096 + 2048);                 \
        f16x8 a3 = *(const f16x8*)(abase + KB * 4096 + 3072);                 \
        union { u32x4 u; f16x8 v; } bb; bb.u = hB[KB];                        \
        acc0 = __builtin_amdgcn_mfma_f32_16x16x32_f16(a0, bb.v, acc0, 0,0,0); \
        acc1 = __builtin_amdgcn_mfma_f32_16x16x32_f16(a1, bb.v, acc1, 0,0,0); \
        acc2 = __builtin_amdgcn_mfma_f32_16x16x32_f16(a2, bb.v, acc2, 0,0,0); \
        acc3 = __builtin_amdgcn_mfma_f32_16x16x32_f16(a3, bb.v, acc3, 0,0,0); \
    } while (0)

    for (int t = 0; t < T; ++t) {
        // ---- per-wave wait: MY 4 producers' flags >= t (dual-chain poll) ----
        if (t) {
            const unsigned tc = (unsigned)t;
            unsigned va, vb;
            PISSUE(va); PISSUE(vb);
            for (;;) {
                asm volatile("s_waitcnt vmcnt(1)" ::: "memory");
                __builtin_amdgcn_sched_barrier(0);
                if (__all((int)(va >= tc))) break;
                PISSUE(va);
                asm volatile("s_waitcnt vmcnt(1)" ::: "memory");
                __builtin_amdgcn_sched_barrier(0);
                if (__all((int)(vb >= tc))) break;
                PISSUE(vb);
            }
            asm volatile("s_waitcnt vmcnt(0)" ::: "memory");  // retire chains
            __builtin_amdgcn_sched_barrier(0);
        }

        const ull rdb = (t & 1) ? hu1 : hu0;
        const ull wrb = (t & 1) ? hu0 : hu1;
        const ull rd  = rdb + (size_t)n * 2048 + wk * 512 + kg * 16;

        u32x4 hB[8];
        f32x4 acc0 = {0.f, 0.f, 0.f, 0.f};
        f32x4 acc1 = {0.f, 0.f, 0.f, 0.f};
        f32x4 acc2 = {0.f, 0.f, 0.f, 0.f};
        f32x4 acc3 = {0.f, 0.f, 0.f, 0.f};

        ISSUE8(hB, rd);
        KSTEP(0, "7"); KSTEP(1, "6"); KSTEP(2, "5"); KSTEP(3, "4");
        KSTEP(4, "3"); KSTEP(5, "2"); KSTEP(6, "1"); KSTEP(7, "0");

        // ---- publish partials (all mf != wk), keep my own ----
        f32x4 mine;
        if (wk == 0) {
            red[0][wn][lane] = acc1; red[1][wn][lane] = acc2;
            red[2][wn][lane] = acc3; mine = acc0;
        } else if (wk == 1) {
            red[3][wn][lane] = acc0; red[4][wn][lane] = acc2;
            red[5][wn][lane] = acc3; mine = acc1;
        } else if (wk == 2) {
            red[6][wn][lane] = acc0; red[7][wn][lane] = acc1;
            red[8][wn][lane] = acc3; mine = acc2;
        } else {
            red[9][wn][lane] = acc0; red[10][wn][lane] = acc1;
            red[11][wn][lane] = acc2; mine = acc3;
        }
        __syncthreads();   // (b) partials visible; union of polls => all 16
                           //     flags >= t => wrb safe to overwrite

        // ---- distributed epilogue: wave (wk,wn) reduces fragment mf=wk ----
        const float xn = xT[(size_t)t * B + n];
        if (wk == 0) {
            mine += red[3][wn][lane]; mine += red[6][wn][lane];
            mine += red[9][wn][lane];
        } else if (wk == 1) {
            mine += red[0][wn][lane]; mine += red[7][wn][lane];
            mine += red[10][wn][lane];
        } else if (wk == 2) {
            mine += red[1][wn][lane]; mine += red[4][wn][lane];
            mine += red[11][wn][lane];
        } else {
            mine += red[2][wn][lane]; mine += red[5][wn][lane];
            mine += red[8][wn][lane];
        }
        union { ull u; f16x4 v; } s_;
        #pragma unroll
        for (int r = 0; r < 4; ++r)
            s_.v[r] = (_Float16)fast_tanh(mine[r] + whxm[r] * xn + bhn);
        // h row-major [n][m]: my fragment at ms*128 + wk*32 + kg*8 bytes
        const ull wr = wrb + (size_t)n * 2048
                     + (size_t)(ms * 128) + wk * 32 + kg * 8;
        G_STORE_X2(wr, s_.u);
        asm volatile("s_waitcnt vmcnt(0)" ::: "memory");  // my store in L2

        __syncthreads();   // (c) whole WG's h(t+1) slice drained
        if (wave == 0 && lane < 16)
            __hip_atomic_store(fpub, (unsigned)(t + 1),
                               __ATOMIC_RELAXED, __HIP_MEMORY_SCOPE_AGENT);
        __builtin_amdgcn_sched_barrier(0);
    }
    #undef KSTEP
}

// ---- final projection: h plain row-major [B][H] ----
__global__ void proj_kernel(const _Float16* __restrict__ hT,
                            const float* __restrict__ Wph,
                            const float* __restrict__ bp,
                            float* __restrict__ out) {
    const int b = blockIdx.x;
    const int lane = threadIdx.x;  // 64
    float partial[NC];
    #pragma unroll
    for (int c = 0; c < NC; ++c) partial[c] = 0.f;
    for (int i = lane; i < H; i += 64) {
        float hv = (float)hT[(size_t)b * H + i];
        #pragma unroll
        for (int c = 0; c < NC; ++c) partial[c] += Wph[(size_t)c * H + i] * hv;
    }
    #pragma unroll
    for (int c = 0; c < NC; ++c) {
        float v = partial[c];
        #pragma unroll
        for (int off = 32; off; off >>= 1) v += __shfl_down(v, off);
        if (lane == 0) out[(size_t)b * NC + c] = v + bp[b];
    }
}

extern "C" void kernel_launch(void* const* d_in, const int* in_sizes, int n_in,
                              void* d_out, int out_size, void* d_ws, size_t ws_size,
                              hipStream_t stream) {
    const float* x   = (const float*)d_in[0];
    const float* Whx = (const float*)d_in[1];
    const float* Whh = (const float*)d_in[2];
    const float* Wph = (const float*)d_in[3];
    const float* bh  = (const float*)d_in[4];
    const float* bp  = (const float*)d_in[5];
    float* out = (float*)d_out;

    char* ws = (char*)d_ws;
    _Float16* Wf    = (_Float16*)ws;                     // 2 MB
    _Float16* h0    = (_Float16*)(ws + (2u << 20));      // 1 MB
    _Float16* h1    = (_Float16*)(ws + (3u << 20));      // 1 MB
    float*    xT    = (float*)(ws + (4u << 20));         // 1 MB
    unsigned* flags = (unsigned*)(ws + (5u << 20));      // 256 KB
    unsigned* claim = (unsigned*)(ws + (5u << 20) + 262144);

    convert_w<<<(H * H / 4) / 256, 256, 0, stream>>>(Whh, Wf);
    transpose_x<<<dim3(T / 32, B / 32), 256, 0, stream>>>(x, xT);
    hipMemsetAsync(h0, 0, (size_t)B * H * 2, stream);
    hipMemsetAsync(flags, 0, 262144 + 256, stream);

    rnn_persist<<<NGROUPS * WPG, NT, 0, stream>>>(Wf, xT, Whx, bh,
                                                  h0, h1, flags, claim);

    // T even -> final h in h0
    proj_kernel<<<B, 64, 0, stream>>>(h0, Wph, bp, out);
}